// Round 17
// baseline (39.388 us; speedup 1.0000x reference)
//
#include <hip/hip_runtime.h>
#include <hip/hip_bf16.h>
#include <hip/hip_fp16.h>

// TransformerEncoderReadout: only the picked atom's output row is needed.
//   QK[b,h,:] = (xp_b.Wq_h + bq_h).Wk_h^T * scale  (q.bk drops out of softmax)
//   s(i,h)    = x_i . QK[b,h,:]; softmax over i within molecule
//   WX[h,:]   = sum_i attn(i,h) x_i      (softmax sums to 1 -> bv folds out)
//   attn_out  = WX . WVO + (bv.Wo) + bo, WVO_h = Wv_h . Wo_h
//   out_row   = LN2(h + FFN(h)),  h = LN1(xp + attn_out)
// R17 = R16 with the wave->tile bug fixed: wave w owns m-tile w (4 waves = all
// 64 molecules), loops all 8 e-tiles (8 unrolled accumulators). R16 covered
// only m-tiles 0-1 -> rows 32-63 read poison (absmax 0.48).

#define BMOL 512

typedef _Float16 v2h __attribute__((ext_vector_type(2)));
typedef _Float16 v8h __attribute__((ext_vector_type(8)));
typedef float f32x4 __attribute__((ext_vector_type(4)));

#if defined(__has_builtin)
#if __has_builtin(__builtin_amdgcn_fdot2)
#define HAVE_FDOT2 1
#endif
#endif
static __device__ __forceinline__ float fdot2f(v2h a, v2h b, float c) {
#ifdef HAVE_FDOT2
    return __builtin_amdgcn_fdot2(a, b, c, false);
#else
    return c + (float)a[0] * (float)b[0] + (float)a[1] * (float)b[1];
#endif
}

// ---------------- K1 block ranges ----------------
// [0,128) WVOp | [128,192) QKh role | [192,224) W1p | [224,256) W2p
// [256,264) bvoP | [264,264+noff) offs
__global__ __launch_bounds__(256) void k_front(
    const float* __restrict__ AF, const float* __restrict__ Wq,
    const float* __restrict__ bq, const float* __restrict__ Wk,
    const float* __restrict__ Wv, const float* __restrict__ Wo,
    const float* __restrict__ bv, const float* __restrict__ W1,
    const float* __restrict__ W2,
    const int* __restrict__ mol, const int* __restrict__ picked,
    int N, int noff,
    int* __restrict__ offs, __half* __restrict__ WVOp,
    float* __restrict__ bvoP, __half* __restrict__ W1p,
    __half* __restrict__ W2p, __half* __restrict__ QKh)
{
    __shared__ float smf[13312];            // 53248 B, role-dependent layout
    int bid = blockIdx.x, t = threadIdx.x;

    if (bid < 128) {
        // ---- WVO tiled GEMM (proven): C[d][c] = sum_kd Wv[d,h,kd]*Wo[h,kd,c] ----
        int h = bid >> 4, tile = bid & 15;
        int dt = tile >> 2, ct = tile & 3;
        float* Avs = smf;                   // [32][33]
        float* Bos = smf + 1056;            // [32][33]
        int ry = t >> 5, cx = t & 31;
        float acc[4] = {0.f, 0.f, 0.f, 0.f};
        for (int kk = 0; kk < 4; ++kk) {
            int r = t >> 3, e0 = (t & 7) * 4;
            float4 va = *(const float4*)(Wv + (size_t)(dt * 32 + r) * 1024 + h * 128 + kk * 32 + e0);
            Avs[r * 33 + e0] = va.x; Avs[r * 33 + e0 + 1] = va.y;
            Avs[r * 33 + e0 + 2] = va.z; Avs[r * 33 + e0 + 3] = va.w;
            float4 vb = *(const float4*)(Wo + (size_t)h * 16384 + (size_t)(kk * 32 + r) * 128 + ct * 32 + e0);
            Bos[r * 33 + e0] = vb.x; Bos[r * 33 + e0 + 1] = vb.y;
            Bos[r * 33 + e0 + 2] = vb.z; Bos[r * 33 + e0 + 3] = vb.w;
            __syncthreads();
            #pragma unroll
            for (int k = 0; k < 32; ++k) {
                float b = Bos[k * 33 + cx];
                #pragma unroll
                for (int i = 0; i < 4; ++i) acc[i] += Avs[(ry * 4 + i) * 33 + k] * b;
            }
            __syncthreads();
        }
        __half2 p0 = __floats2half2_rn(acc[0], acc[1]);
        __half2 p1 = __floats2half2_rn(acc[2], acc[3]);
        __half* dst = WVOp + (size_t)(h * 16 + dt * 4 + (ry >> 1)) * 1024
                           + (ct * 32 + cx) * 8 + (ry & 1) * 4;
        ((__half2*)dst)[0] = p0; ((__half2*)dst)[1] = p1;
        return;
    }
    bid -= 128;
    if (bid < 64) {
        // ---- QKh role: head h, molecules [m0,m0+64). All LDS-staged. ----
        int h = bid >> 3, mg = bid & 7;
        int m0 = mg * 64;
        _Float16* R1   = (_Float16*)smf;                    // [128][136] 34816B: WqT then WkL
        _Float16* R2   = (_Float16*)((char*)smf + 34816);   // [64][136]  17408B: xpl then qL
        int*      rows = (int*)((char*)smf + 52224);        // [64]
        const float scale = 0.08838834764831843f;           // 1/sqrt(128)
        int l = t & 63, l15 = l & 15, qq = l >> 4;
        int w = t >> 6;                     // wave = m-tile (0..3)
        if (t < 64) {                       // picked row via lower_bound(mol, m)
            int m = m0 + t, lo = 0, hi = N;
            while (lo < hi) { int mid = (lo + hi) >> 1; if (mol[mid] < m) lo = mid + 1; else hi = mid; }
            rows[t] = lo + picked[m];
        }
        for (int p = t; p < 16384; p += 256) {  // WqT[e][k] = Wq[k][h*128+e] (coalesced read)
            int k = p >> 7, e = p & 127;
            R1[e * 136 + k] = (_Float16)Wq[(size_t)k * 1024 + h * 128 + e];
        }
        __syncthreads();                    // rows + WqT ready
        for (int p = t; p < 2048; p += 256) {   // xpl[m][d] fp16 (64 rows x 32 float4)
            int m = p >> 5, d4 = p & 31;
            float4 v = ((const float4*)(AF + (size_t)rows[m] * 128))[d4];
            float2 st;
            ((__half2*)&st)[0] = __floats2half2_rn(v.x, v.y);
            ((__half2*)&st)[1] = __floats2half2_rn(v.z, v.w);
            *(float2*)(&R2[m * 136 + d4 * 4]) = st;
        }
        __syncthreads();                    // xpl ready
        f32x4 acc[8];
        #pragma unroll
        for (int i = 0; i < 8; ++i) acc[i] = (f32x4){0.f, 0.f, 0.f, 0.f};
        #pragma unroll
        for (int ks = 0; ks < 4; ++ks) {    // GEMM1: q = xp . Wq_h  (wave w = m-tile w)
            v8h a = *(const v8h*)(&R2[(w * 16 + l15) * 136 + ks * 32 + qq * 8]);
            #pragma unroll
            for (int et = 0; et < 8; ++et) {
                v8h bf = *(const v8h*)(&R1[(et * 16 + l15) * 136 + ks * 32 + qq * 8]);
                acc[et] = __builtin_amdgcn_mfma_f32_16x16x32_f16(a, bf, acc[et], 0, 0, 0);
            }
        }
        __syncthreads();                    // all GEMM1 reads done
        #pragma unroll
        for (int et = 0; et < 8; ++et) {    // qL[m][e] = q + bq (fp16), into R2
            #pragma unroll
            for (int r = 0; r < 4; ++r) {
                int m = w * 16 + qq * 4 + r;
                int e = et * 16 + l15;
                R2[m * 136 + e] = (_Float16)(acc[et][r] + bq[h * 128 + e]);
            }
        }
        for (int p = t; p < 16384; p += 256) {  // WkL[d][a] = Wk[d][h*128+a] (both coalesced)
            int d = p >> 7, a = p & 127;
            R1[d * 136 + a] = (_Float16)Wk[(size_t)d * 1024 + h * 128 + a];
        }
        __syncthreads();                    // qL + WkL ready
        #pragma unroll
        for (int i = 0; i < 8; ++i) acc[i] = (f32x4){0.f, 0.f, 0.f, 0.f};
        #pragma unroll
        for (int ks = 0; ks < 4; ++ks) {    // GEMM2: QK = q . Wk_h^T
            v8h a = *(const v8h*)(&R2[(w * 16 + l15) * 136 + ks * 32 + qq * 8]);
            #pragma unroll
            for (int et = 0; et < 8; ++et) {
                v8h bf = *(const v8h*)(&R1[(et * 16 + l15) * 136 + ks * 32 + qq * 8]);
                acc[et] = __builtin_amdgcn_mfma_f32_16x16x32_f16(a, bf, acc[et], 0, 0, 0);
            }
        }
        #pragma unroll
        for (int et = 0; et < 8; ++et) {    // D: col=d (et*16+l15), row=m (w*16+qq*4+r)
            #pragma unroll
            for (int r = 0; r < 4; ++r) {
                int m = w * 16 + qq * 4 + r;
                int d = et * 16 + l15;
                QKh[(size_t)(m0 + m) * 1024 + h * 128 + d] = (__half)(acc[et][r] * scale);
            }
        }
        return;
    }
    bid -= 64;
    if (bid < 32) {                         // W1p[(k>>3)][f][k&7], K=128, F=512
        int g = bid * 256 + t;
        int kg = g >> 9, f = g & 511;
        __half2 p[4];
        #pragma unroll
        for (int j = 0; j < 4; ++j) {
            float a = W1[(size_t)(kg * 8 + 2 * j) * 512 + f];
            float b = W1[(size_t)(kg * 8 + 2 * j + 1) * 512 + f];
            p[j] = __floats2half2_rn(a, b);
        }
        *(float4*)(W1p + (size_t)kg * 4096 + f * 8) = *(float4*)p;
        return;
    }
    bid -= 32;
    if (bid < 32) {                         // W2p[(f>>3)][c][f&7], K=512, C=128
        int g = bid * 256 + t;
        int fg = g >> 7, c = g & 127;
        __half2 p[4];
        #pragma unroll
        for (int j = 0; j < 4; ++j) {
            float a = W2[(size_t)(fg * 8 + 2 * j) * 128 + c];
            float b = W2[(size_t)(fg * 8 + 2 * j + 1) * 128 + c];
            p[j] = __floats2half2_rn(a, b);
        }
        *(float4*)(W2p + (size_t)fg * 1024 + c * 8) = *(float4*)p;
        return;
    }
    bid -= 32;
    if (bid < 8) {                          // bvoP[j][c] = sum_{hk in j-th 128} bv[hk]*Wo[hk,c]
        int half = t >> 7, c = t & 127;
        float acc = 0.f;
        #pragma unroll 4
        for (int kk = 0; kk < 64; ++kk) {
            int k = bid * 128 + half * 64 + kk;
            acc += bv[k] * Wo[(size_t)k * 128 + c];
        }
        smf[half * 128 + c] = acc;
        __syncthreads();
        if (t < 128) bvoP[bid * 128 + t] = smf[t] + smf[128 + t];
        return;
    }
    bid -= 8;
    {                                       // offs scan
        int i = bid * 256 + t;
        if (i < N) {
            if (i == 0) { offs[0] = 0; offs[BMOL] = N; }
            else if (mol[i] != mol[i - 1]) offs[mol[i]] = i;
        }
    }
}

// ---------------- K2: MFMA attention + tail, one block per molecule ----------------
__global__ __launch_bounds__(512) void k_attn_tail(
    const float* __restrict__ AF, const int* __restrict__ offs,
    const int* __restrict__ picked, const __half* __restrict__ QKh,
    const __half* __restrict__ WVOp, const float* __restrict__ bvoP,
    const float* __restrict__ bo,
    const float* __restrict__ g1, const float* __restrict__ be1,
    const __half* __restrict__ W1p, const float* __restrict__ b1,
    const __half* __restrict__ W2p, const float* __restrict__ b2,
    const float* __restrict__ g2, const float* __restrict__ be2,
    float* __restrict__ out)
{
    int b = blockIdx.x, t = threadIdx.x;
    int o0 = offs[b], cnt = offs[b + 1] - o0;
    int cpad = ((cnt + 31) >> 5) << 5;      // K-pad (multiple of 32) for WX MFMA
    __shared__ _Float16 xs[128][136];       // fp16 X; rows cnt..cpad zeroed
    __shared__ _Float16 qsh[16][136];       // scaled QK (from QKh); rows 8-15 zero
    __shared__ float s[8 * 136];            // raw scores
    __shared__ _Float16 Ph[16][136];        // softmaxed attn fp16; rows 8-15 zero
    __shared__ float mh[8], lh[8];
    __shared__ _Float16 wsh[1024];          // WX fp16
    __shared__ float part[4][128];          // wave-uniform K-split partials
    __shared__ float xp[128];               // picked row fp32 (residual)
    __shared__ float h1raw[128], h1n[128];
    __shared__ _Float16 h1nh[128];
    __shared__ _Float16 msh[512];

    const float4* af4 = (const float4*)(AF + (size_t)o0 * 128);
    for (int p = t; p < cnt * 32; p += 512) {   // stage X once, f32->f16
        int i = p >> 5, d4 = p & 31;
        float4 v = af4[p];
        float2 st;
        ((__half2*)&st)[0] = __floats2half2_rn(v.x, v.y);
        ((__half2*)&st)[1] = __floats2half2_rn(v.z, v.w);
        *(float2*)(&xs[i][d4 * 4]) = st;
    }
    for (int p = cnt * 32 + t; p < cpad * 32; p += 512) {   // zero pad rows
        int i = p >> 5, d4 = p & 31;
        float2 z = {0.f, 0.f};
        *(float2*)(&xs[i][d4 * 4]) = z;
    }
    for (int p = t; p < 544; p += 512) {    // zero qsh/Ph rows 8-15
        ((unsigned*)&qsh[8][0])[p] = 0u;
        ((unsigned*)&Ph[8][0])[p] = 0u;
    }
    if (t < 128) {                          // stage QKh row (1KB, bq+scale folded)
        float4 ld = ((const float4*)(QKh + (size_t)b * 1024))[t];
        int hh = t >> 4, d0 = (t & 15) * 8;
        *(float4*)(&qsh[hh][d0]) = ld;
    }
    if (t < 128) xp[t] = AF[(size_t)(o0 + picked[b]) * 128 + t];
    __syncthreads();
    {   // ---- scores via MFMA: wave w -> rows [w*16, w*16+16), 16 head-cols ----
        int w = t >> 6, l = t & 63;
        int i0 = w * 16;
        if (i0 < cnt) {
            int arow = i0 + (l & 15);
            int q = l >> 4;
            f32x4 acc = {0.f, 0.f, 0.f, 0.f};
            #pragma unroll
            for (int ks = 0; ks < 4; ++ks) {
                v8h a  = *(const v8h*)(&xs[arow][ks * 32 + q * 8]);
                v8h bf = *(const v8h*)(&qsh[l & 15][ks * 32 + q * 8]);
                acc = __builtin_amdgcn_mfma_f32_16x16x32_f16(a, bf, acc, 0, 0, 0);
            }
            if ((l & 15) < 8) {             // D: col=lane&15 (head), row=q*4+r (atom)
                #pragma unroll
                for (int r = 0; r < 4; ++r)
                    s[(l & 15) * 136 + i0 + q * 4 + r] = acc[r];
            }
        }
    }
    __syncthreads();
    {   // softmax stats: one 64-lane wave per head
        int h = t >> 6, lane = t & 63;
        float m = -1e30f;
        for (int i = lane; i < cnt; i += 64) m = fmaxf(m, s[h * 136 + i]);
        #pragma unroll
        for (int off = 32; off; off >>= 1) m = fmaxf(m, __shfl_xor(m, off));
        float l = 0.f;
        for (int i = lane; i < cnt; i += 64) l += __expf(s[h * 136 + i] - m);
        #pragma unroll
        for (int off = 32; off; off >>= 1) l += __shfl_xor(l, off);
        if (lane == 0) { mh[h] = m; lh[h] = 1.f / l; }
    }
    __syncthreads();
    for (int p = t; p < cpad * 8; p += 512) {   // P = exp(s-m)*linv, fp16, zero-padded
        int i = p >> 3, h = p & 7;
        float v = (i < cnt) ? __expf(s[h * 136 + i] - mh[h]) * lh[h] : 0.f;
        Ph[h][i] = (_Float16)v;
    }
    __syncthreads();
    {   // ---- WX via MFMA: wave w -> d-cols [w*16, w*16+16) ----
        int w = t >> 6, l = t & 63;
        int q = l >> 4;
        int d0 = w * 16 + (l & 15);
        int nks = cpad >> 5;
        f32x4 acc = {0.f, 0.f, 0.f, 0.f};
        for (int ks = 0; ks < nks; ++ks) {
            int k0 = ks * 32 + q * 8;
            v8h a = *(const v8h*)(&Ph[l & 15][k0]);     // A row = head = lane&15
            v8h bf;
            #pragma unroll
            for (int j = 0; j < 8; ++j) bf[j] = xs[k0 + j][d0];  // B col = d = lane&15
            acc = __builtin_amdgcn_mfma_f32_16x16x32_f16(a, bf, acc, 0, 0, 0);
        }
        #pragma unroll
        for (int r = 0; r < 4; ++r) {       // D: col=d, row=q*4+r = head
            int h = q * 4 + r;
            if (h < 8) wsh[h * 128 + d0] = (_Float16)acc[r];
        }
    }
    __syncthreads();
    // wave-uniform K-split: kq constant per wave -> LDS reads broadcast
    int wv = t >> 6, lane = t & 63;
    int kq = wv & 3, ch = wv >> 2;
    int c = ch * 64 + lane;
    {   // tail A: attn_out[c] = wsh . WVO[:,c], K=1024 in 4 wave-chunks
        const __half* wp = WVOp + ((size_t)(kq * 32) * 128 + c) * 8;
        const v2h* wk = (const v2h*)wsh + kq * 128;
        float acc = 0.f;
        #pragma unroll 8
        for (int g = 0; g < 32; ++g) {
            float4 raw = *(const float4*)(wp + (size_t)g * 1024);
            const v2h* hp = (const v2h*)&raw;
            acc = fdot2f(hp[0], wk[g * 4 + 0], acc);
            acc = fdot2f(hp[1], wk[g * 4 + 1], acc);
            acc = fdot2f(hp[2], wk[g * 4 + 2], acc);
            acc = fdot2f(hp[3], wk[g * 4 + 3], acc);
        }
        part[kq][c] = acc;
    }
    __syncthreads();
    if (t < 128) {
        float acc = part[0][t] + part[1][t] + part[2][t] + part[3][t];
        float bias = bo[t];
        #pragma unroll
        for (int j = 0; j < 8; ++j) bias += bvoP[j * 128 + t];
        h1raw[t] = acc + bias + xp[t];
    }
    __syncthreads();
    {   // LN1 (redundant per wave)
        int l = t & 63;
        float a = h1raw[l], bb = h1raw[l + 64];
        float sm = a + bb, sq = a * a + bb * bb;
        #pragma unroll
        for (int off = 32; off; off >>= 1) { sm += __shfl_xor(sm, off); sq += __shfl_xor(sq, off); }
        float m = sm * (1.f / 128.f), var = sq * (1.f / 128.f) - m * m;
        float rs = rsqrtf(var + 1e-3f);
        if (t < 128) {
            float v = (h1raw[t] - m) * rs * g1[t] + be1[t];
            h1n[t] = v; h1nh[t] = (_Float16)v;
        }
    }
    __syncthreads();
    {   // phase B: msh[f] = relu(h1nh . W1[:,f] + b1), one output per thread
        const __half* wp = W1p + t * 8;
        const v2h* hk = (const v2h*)h1nh;
        float acc = 0.f;
        #pragma unroll 8
        for (int kg = 0; kg < 16; ++kg) {
            float4 raw = *(const float4*)(wp + (size_t)kg * 4096);
            const v2h* hp = (const v2h*)&raw;
            acc = fdot2f(hp[0], hk[kg * 4 + 0], acc);
            acc = fdot2f(hp[1], hk[kg * 4 + 1], acc);
            acc = fdot2f(hp[2], hk[kg * 4 + 2], acc);
            acc = fdot2f(hp[3], hk[kg * 4 + 3], acc);
        }
        msh[t] = (_Float16)fmaxf(acc + b1[t], 0.f);
    }
    __syncthreads();
    {   // phase C: out[c] = msh . W2[:,c] + b2 + h1n, K=512 in 4 wave-chunks
        const __half* wp = W2p + ((size_t)(kq * 16) * 128 + c) * 8;
        const v2h* mk = (const v2h*)msh + kq * 64;
        float acc = 0.f;
        #pragma unroll 8
        for (int g = 0; g < 16; ++g) {
            float4 raw = *(const float4*)(wp + (size_t)g * 1024);
            const v2h* hp = (const v2h*)&raw;
            acc = fdot2f(hp[0], mk[g * 4 + 0], acc);
            acc = fdot2f(hp[1], mk[g * 4 + 1], acc);
            acc = fdot2f(hp[2], mk[g * 4 + 2], acc);
            acc = fdot2f(hp[3], mk[g * 4 + 3], acc);
        }
        part[kq][c] = acc;
    }
    __syncthreads();
    if (t < 128) {
        float acc = part[0][t] + part[1][t] + part[2][t] + part[3][t];
        h1raw[t] = acc + b2[t] + h1n[t];
    }
    __syncthreads();
    {   // LN2 (redundant per wave) -> global out
        int l = t & 63;
        float a = h1raw[l], bb = h1raw[l + 64];
        float sm = a + bb, sq = a * a + bb * bb;
        #pragma unroll
        for (int off = 32; off; off >>= 1) { sm += __shfl_xor(sm, off); sq += __shfl_xor(sq, off); }
        float m = sm * (1.f / 128.f), var = sq * (1.f / 128.f) - m * m;
        float rs = rsqrtf(var + 1e-3f);
        if (t < 128) out[(size_t)b * 128 + t] = (h1raw[t] - m) * rs * g2[t] + be2[t];
    }
}

extern "C" void kernel_launch(void* const* d_in, const int* in_sizes, int n_in,
                              void* d_out, int out_size, void* d_ws, size_t ws_size,
                              hipStream_t stream) {
    const float* AF  = (const float*)d_in[0];
    const float* Wq  = (const float*)d_in[1];
    const float* bq  = (const float*)d_in[2];
    const float* Wk  = (const float*)d_in[3];
    const float* Wv  = (const float*)d_in[5];
    const float* bv  = (const float*)d_in[6];
    const float* Wo  = (const float*)d_in[7];
    const float* bo  = (const float*)d_in[8];
    const float* W1  = (const float*)d_in[9];
    const float* b1  = (const float*)d_in[10];
    const float* W2  = (const float*)d_in[11];
    const float* b2  = (const float*)d_in[12];
    const float* g1  = (const float*)d_in[13];
    const float* be1 = (const float*)d_in[14];
    const float* g2  = (const float*)d_in[15];
    const float* be2 = (const float*)d_in[16];
    const int* mol    = (const int*)d_in[17];
    const int* picked = (const int*)d_in[18];
    int N = in_sizes[0] / 128;
    int noff = (N + 255) / 256;

    char* ws = (char*)d_ws;
    int*    offs = (int*)ws;                      // 513 ints (4KB slot)
    __half* WVOp = (__half*)(ws + 4096);          // packed [128][128][8] 256KB
    float*  bvoP = (float*)(ws + 266240);         // [8][128] 4KB
    __half* W1p  = (__half*)(ws + 270336);        // packed [16][512][8] 128KB
    __half* W2p  = (__half*)(ws + 401408);        // packed [64][128][8] 128KB
    __half* QKh  = (__half*)(ws + 532480);        // [512][1024] fp16 1MB

    k_front<<<264 + noff, 256, 0, stream>>>(AF, Wq, bq, Wk, Wv, Wo, bv, W1, W2,
                                            mol, picked, N, noff,
                                            offs, WVOp, bvoP, W1p, W2p, QKh);
    k_attn_tail<<<BMOL, 512, 0, stream>>>(AF, offs, picked, QKh,
                                          WVOp, bvoP, bo, g1, be1, W1p, b1,
                                          W2p, b2, g2, be2, (float*)d_out);
}

// Round 18
// 32.389 us; speedup vs baseline: 1.2161x; 1.2161x over previous
//
#include <hip/hip_runtime.h>
#include <hip/hip_bf16.h>
#include <hip/hip_fp16.h>

// TransformerEncoderReadout: only the picked atom's output row is needed.
//   QK[b,h,:] = xp_b . WQK_h + bqk_h,   WQK_h = Wq_h . Wk_h^T  (q.bk drops out)
//   s(i,h)    = x_i . QK[b,h,:] / sqrt(128); softmax over i within molecule
//   WX[h,:]   = sum_i attn(i,h) x_i      (softmax sums to 1 -> bv folds out)
//   attn_out  = WX . WVO + (bv.Wo) + bo, WVO_h = Wv_h . Wo_h
//   out_row   = LN2(h + FFN(h)),  h = LN1(xp + attn_out)
// R18 = R12 verbatim (verified best, 32.6us). All post-R12 levers lost:
// tail-split (R9 45), prefetch-spill (R10 51), ILP chains (R15 34.3),
// QKh-in-K1 x3 (R8 61, R14 57, R17 39.4). K2 is stall-bound at 2 blocks/CU;
// removing L2-hidden work doesn't pay; structural re-partitions add more
// serialization than they remove.

#define BMOL 512

typedef _Float16 v2h __attribute__((ext_vector_type(2)));
typedef _Float16 v8h __attribute__((ext_vector_type(8)));
typedef float f32x4 __attribute__((ext_vector_type(4)));

#if defined(__has_builtin)
#if __has_builtin(__builtin_amdgcn_fdot2)
#define HAVE_FDOT2 1
#endif
#endif
static __device__ __forceinline__ float fdot2f(v2h a, v2h b, float c) {
#ifdef HAVE_FDOT2
    return __builtin_amdgcn_fdot2(a, b, c, false);
#else
    return c + (float)a[0] * (float)b[0] + (float)a[1] * (float)b[1];
#endif
}

// ---------------- K1 block ranges ----------------
// [0,128) WVOp | [128,256) WQKp | [256,288) W1p | [288,320) W2p
// [320,328) bvoP | [328,336) bqk | [336,336+noff) offs
__global__ __launch_bounds__(256) void k_front(
    const float* __restrict__ Wq, const float* __restrict__ bq,
    const float* __restrict__ Wk, const float* __restrict__ Wv,
    const float* __restrict__ Wo, const float* __restrict__ bv,
    const float* __restrict__ W1, const float* __restrict__ W2,
    const int* __restrict__ mol, int N, int noff,
    int* __restrict__ offs, __half* __restrict__ WVOp,
    __half* __restrict__ WQKp, float* __restrict__ bqk,
    float* __restrict__ bvoP, __half* __restrict__ W1p, __half* __restrict__ W2p)
{
    __shared__ float lds[2176];             // 2x [32][33] tiles
    int bid = blockIdx.x, t = threadIdx.x;

    if (bid < 256) {
        // ---- tiled GEMM: 32x32 output tile, K=128 ----
        // bid<128: WVO[(h*128+d)][c] = sum_kd Wv[d,h,kd]*Wo[h,kd,c]
        // else   : WQK[(h*128+k)][d] = sum_kd Wq[k,h,kd]*Wk[d,h,kd]
        bool qk = bid >= 128;
        int rel = bid & 127;
        int h = rel >> 4, tile = rel & 15;
        int dt = tile >> 2, ct = tile & 3;
        float* Avs = lds;                   // [32][33]
        float* Bos = lds + 1056;            // [32][33]
        int ry = t >> 5, cx = t & 31;
        float acc[4] = {0.f, 0.f, 0.f, 0.f};
        const float* Asrc = qk ? Wq : Wv;
        for (int kk = 0; kk < 4; ++kk) {
            int r = t >> 3, e0 = (t & 7) * 4;
            float4 va = *(const float4*)(Asrc + (size_t)(dt * 32 + r) * 1024 + h * 128 + kk * 32 + e0);
            Avs[r * 33 + e0] = va.x; Avs[r * 33 + e0 + 1] = va.y;
            Avs[r * 33 + e0 + 2] = va.z; Avs[r * 33 + e0 + 3] = va.w;
            if (qk) {                       // B[kd][d] = Wk[d,h,kd] (transposed load)
                float4 vb = *(const float4*)(Wk + (size_t)(ct * 32 + r) * 1024 + h * 128 + kk * 32 + e0);
                Bos[(e0 + 0) * 33 + r] = vb.x;
                Bos[(e0 + 1) * 33 + r] = vb.y;
                Bos[(e0 + 2) * 33 + r] = vb.z;
                Bos[(e0 + 3) * 33 + r] = vb.w;
            } else {                        // B[kd][c] = Wo[h,kd,c]
                float4 vb = *(const float4*)(Wo + (size_t)h * 16384 + (size_t)(kk * 32 + r) * 128 + ct * 32 + e0);
                Bos[r * 33 + e0] = vb.x; Bos[r * 33 + e0 + 1] = vb.y;
                Bos[r * 33 + e0 + 2] = vb.z; Bos[r * 33 + e0 + 3] = vb.w;
            }
            __syncthreads();
            #pragma unroll
            for (int k = 0; k < 32; ++k) {
                float b = Bos[k * 33 + cx];
                #pragma unroll
                for (int i = 0; i < 4; ++i) acc[i] += Avs[(ry * 4 + i) * 33 + k] * b;
            }
            __syncthreads();
        }
        __half2 p0 = __floats2half2_rn(acc[0], acc[1]);
        __half2 p1 = __floats2half2_rn(acc[2], acc[3]);
        __half* dst = (qk ? WQKp : WVOp)
                    + (size_t)(h * 16 + dt * 4 + (ry >> 1)) * 1024
                    + (ct * 32 + cx) * 8 + (ry & 1) * 4;
        ((__half2*)dst)[0] = p0; ((__half2*)dst)[1] = p1;
        return;
    }
    bid -= 256;
    if (bid < 32) {                         // W1p[(k>>3)][f][k&7], K=128, F=512
        int g = bid * 256 + t;
        int kg = g >> 9, f = g & 511;
        __half2 p[4];
        #pragma unroll
        for (int j = 0; j < 4; ++j) {
            float a = W1[(size_t)(kg * 8 + 2 * j) * 512 + f];
            float b = W1[(size_t)(kg * 8 + 2 * j + 1) * 512 + f];
            p[j] = __floats2half2_rn(a, b);
        }
        *(float4*)(W1p + (size_t)kg * 4096 + f * 8) = *(float4*)p;
        return;
    }
    bid -= 32;
    if (bid < 32) {                         // W2p[(f>>3)][c][f&7], K=512, C=128
        int g = bid * 256 + t;
        int fg = g >> 7, c = g & 127;
        __half2 p[4];
        #pragma unroll
        for (int j = 0; j < 4; ++j) {
            float a = W2[(size_t)(fg * 8 + 2 * j) * 128 + c];
            float b = W2[(size_t)(fg * 8 + 2 * j + 1) * 128 + c];
            p[j] = __floats2half2_rn(a, b);
        }
        *(float4*)(W2p + (size_t)fg * 1024 + c * 8) = *(float4*)p;
        return;
    }
    bid -= 32;
    if (bid < 8) {                          // bvoP[j][c] = sum_{hk in j-th 128} bv[hk]*Wo[hk,c]
        int half = t >> 7, c = t & 127;
        float acc = 0.f;
        #pragma unroll 4
        for (int kk = 0; kk < 64; ++kk) {
            int k = bid * 128 + half * 64 + kk;
            acc += bv[k] * Wo[(size_t)k * 128 + c];
        }
        lds[half * 128 + c] = acc;
        __syncthreads();
        if (t < 128) bvoP[bid * 128 + t] = lds[t] + lds[128 + t];
        return;
    }
    bid -= 8;
    if (bid < 8) {                          // bqk[h][d] = sum_kd bq[h,kd]*Wk[d,h,kd]
        int h = bid;
        if (t < 128) {
            const float* wk = Wk + (size_t)t * 1024 + h * 128;
            const float* bqh = bq + h * 128;
            float acc = 0.f;
            #pragma unroll 4
            for (int kd = 0; kd < 128; ++kd) acc += bqh[kd] * wk[kd];
            bqk[h * 128 + t] = acc;
        }
        return;
    }
    bid -= 8;
    {                                       // offs scan
        int i = bid * 256 + t;
        if (i < N) {
            if (i == 0) { offs[0] = 0; offs[BMOL] = N; }
            else if (mol[i] != mol[i - 1]) offs[mol[i]] = i;
        }
    }
}

// ---------------- K2: fused QK + MFMA attention + tail, one block per molecule ----------------
__global__ __launch_bounds__(512) void k_attn_tail(
    const float* __restrict__ AF, const int* __restrict__ offs,
    const int* __restrict__ picked,
    const __half* __restrict__ WQKp, const float* __restrict__ bqk,
    const __half* __restrict__ WVOp, const float* __restrict__ bvoP,
    const float* __restrict__ bo,
    const float* __restrict__ g1, const float* __restrict__ be1,
    const __half* __restrict__ W1p, const float* __restrict__ b1,
    const __half* __restrict__ W2p, const float* __restrict__ b2,
    const float* __restrict__ g2, const float* __restrict__ be2,
    float* __restrict__ out)
{
    int b = blockIdx.x, t = threadIdx.x;
    int o0 = offs[b], cnt = offs[b + 1] - o0;
    int cpad = ((cnt + 31) >> 5) << 5;      // K-pad (multiple of 32) for WX MFMA
    __shared__ _Float16 xs[128][136];       // fp16 X; rows cnt..cpad zeroed
    __shared__ _Float16 qsh[16][136];       // scaled QK; rows 8-15 zero
    __shared__ float s[8 * 136];            // raw scores
    __shared__ _Float16 Ph[16][136];        // softmaxed attn fp16; rows 8-15 zero
    __shared__ float mh[8], lh[8];
    __shared__ _Float16 wsh[1024];          // WX fp16
    __shared__ float part[4][128];          // wave-uniform K-split partials
    __shared__ float xp[128];               // picked row fp32 (residual)
    __shared__ _Float16 xph[128];           // picked row fp16 (QK dot)
    __shared__ float h1raw[128], h1n[128];
    __shared__ _Float16 h1nh[128];
    __shared__ _Float16 msh[512];
    const float scale = 0.08838834764831843f;   // 1/sqrt(128)

    const float4* af4 = (const float4*)(AF + (size_t)o0 * 128);
    for (int p = t; p < cnt * 32; p += 512) {   // stage X once, f32->f16
        int i = p >> 5, d4 = p & 31;
        float4 v = af4[p];
        float2 st;
        ((__half2*)&st)[0] = __floats2half2_rn(v.x, v.y);
        ((__half2*)&st)[1] = __floats2half2_rn(v.z, v.w);
        *(float2*)(&xs[i][d4 * 4]) = st;
    }
    for (int p = cnt * 32 + t; p < cpad * 32; p += 512) {   // zero pad rows
        int i = p >> 5, d4 = p & 31;
        float2 z = {0.f, 0.f};
        *(float2*)(&xs[i][d4 * 4]) = z;
    }
    for (int p = t; p < 544; p += 512) {    // zero qsh/Ph rows 8-15 (8*136 halves = 544 dwords)
        ((unsigned*)&qsh[8][0])[p] = 0u;
        ((unsigned*)&Ph[8][0])[p] = 0u;
    }
    if (t < 128) {
        float v = AF[(size_t)(o0 + picked[b]) * 128 + t];
        xp[t] = v; xph[t] = (_Float16)v;
    }
    __syncthreads();
    {   // ---- QK row: qsh[h][d] = (xph . WQK_h[:,d] + bqk)*scale ----
        int h = t >> 6, d0 = (t & 63) * 2;
        const __half* wp = WQKp + ((size_t)(h * 16) * 128 + d0) * 8;
        const v2h* xh = (const v2h*)xph;    // broadcast reads (wave-uniform addr)
        float a0 = 0.f, a1 = 0.f;
        #pragma unroll 4
        for (int kg = 0; kg < 16; ++kg) {
            float4 r0 = *(const float4*)(wp + (size_t)kg * 1024);
            float4 r1 = *(const float4*)(wp + (size_t)kg * 1024 + 8);
            const v2h* h0 = (const v2h*)&r0;
            const v2h* h1 = (const v2h*)&r1;
            #pragma unroll
            for (int j = 0; j < 4; ++j) {
                v2h xv = xh[kg * 4 + j];
                a0 = fdot2f(xv, h0[j], a0);
                a1 = fdot2f(xv, h1[j], a1);
            }
        }
        qsh[h][d0]     = (_Float16)((a0 + bqk[h * 128 + d0]) * scale);
        qsh[h][d0 + 1] = (_Float16)((a1 + bqk[h * 128 + d0 + 1]) * scale);
    }
    __syncthreads();
    {   // ---- scores via MFMA: wave w -> rows [w*16, w*16+16), 16 head-cols ----
        int w = t >> 6, l = t & 63;
        int i0 = w * 16;
        if (i0 < cnt) {
            int arow = i0 + (l & 15);
            int q = l >> 4;
            f32x4 acc = {0.f, 0.f, 0.f, 0.f};
            #pragma unroll
            for (int ks = 0; ks < 4; ++ks) {
                v8h a  = *(const v8h*)(&xs[arow][ks * 32 + q * 8]);
                v8h bf = *(const v8h*)(&qsh[l & 15][ks * 32 + q * 8]);
                acc = __builtin_amdgcn_mfma_f32_16x16x32_f16(a, bf, acc, 0, 0, 0);
            }
            if ((l & 15) < 8) {             // D: col=lane&15 (head), row=q*4+r (atom)
                #pragma unroll
                for (int r = 0; r < 4; ++r)
                    s[(l & 15) * 136 + i0 + q * 4 + r] = acc[r];
            }
        }
    }
    __syncthreads();
    {   // softmax stats: one 64-lane wave per head
        int h = t >> 6, lane = t & 63;
        float m = -1e30f;
        for (int i = lane; i < cnt; i += 64) m = fmaxf(m, s[h * 136 + i]);
        #pragma unroll
        for (int off = 32; off; off >>= 1) m = fmaxf(m, __shfl_xor(m, off));
        float l = 0.f;
        for (int i = lane; i < cnt; i += 64) l += __expf(s[h * 136 + i] - m);
        #pragma unroll
        for (int off = 32; off; off >>= 1) l += __shfl_xor(l, off);
        if (lane == 0) { mh[h] = m; lh[h] = 1.f / l; }
    }
    __syncthreads();
    for (int p = t; p < cpad * 8; p += 512) {   // P = exp(s-m)*linv, fp16, zero-padded
        int i = p >> 3, h = p & 7;
        float v = (i < cnt) ? __expf(s[h * 136 + i] - mh[h]) * lh[h] : 0.f;
        Ph[h][i] = (_Float16)v;
    }
    __syncthreads();
    {   // ---- WX via MFMA: wave w -> d-cols [w*16, w*16+16) ----
        int w = t >> 6, l = t & 63;
        int q = l >> 4;
        int d0 = w * 16 + (l & 15);
        int nks = cpad >> 5;
        f32x4 acc = {0.f, 0.f, 0.f, 0.f};
        for (int ks = 0; ks < nks; ++ks) {
            int k0 = ks * 32 + q * 8;
            v8h a = *(const v8h*)(&Ph[l & 15][k0]);     // A row = head = lane&15
            v8h bf;
            #pragma unroll
            for (int j = 0; j < 8; ++j) bf[j] = xs[k0 + j][d0];  // B col = d = lane&15
            acc = __builtin_amdgcn_mfma_f32_16x16x32_f16(a, bf, acc, 0, 0, 0);
        }
        #pragma unroll
        for (int r = 0; r < 4; ++r) {       // D: col=d, row=q*4+r = head
            int h = q * 4 + r;
            if (h < 8) wsh[h * 128 + d0] = (_Float16)acc[r];
        }
    }
    __syncthreads();
    // wave-uniform K-split: kq constant per wave -> LDS reads broadcast
    int wv = t >> 6, lane = t & 63;
    int kq = wv & 3, ch = wv >> 2;
    int c = ch * 64 + lane;
    {   // tail A: attn_out[c] = wsh . WVO[:,c], K=1024 in 4 wave-chunks
        const __half* wp = WVOp + ((size_t)(kq * 32) * 128 + c) * 8;
        const v2h* wk = (const v2h*)wsh + kq * 128;
        float acc = 0.f;
        #pragma unroll 8
        for (int g = 0; g < 32; ++g) {
            float4 raw = *(const float4*)(wp + (size_t)g * 1024);
            const v2h* hp = (const v2h*)&raw;
            acc = fdot2f(hp[0], wk[g * 4 + 0], acc);
            acc = fdot2f(hp[1], wk[g * 4 + 1], acc);
            acc = fdot2f(hp[2], wk[g * 4 + 2], acc);
            acc = fdot2f(hp[3], wk[g * 4 + 3], acc);
        }
        part[kq][c] = acc;
    }
    __syncthreads();
    if (t < 128) {
        float acc = part[0][t] + part[1][t] + part[2][t] + part[3][t];
        float bias = bo[t];
        #pragma unroll
        for (int j = 0; j < 8; ++j) bias += bvoP[j * 128 + t];
        h1raw[t] = acc + bias + xp[t];
    }
    __syncthreads();
    {   // LN1 (redundant per wave)
        int l = t & 63;
        float a = h1raw[l], bb = h1raw[l + 64];
        float sm = a + bb, sq = a * a + bb * bb;
        #pragma unroll
        for (int off = 32; off; off >>= 1) { sm += __shfl_xor(sm, off); sq += __shfl_xor(sq, off); }
        float m = sm * (1.f / 128.f), var = sq * (1.f / 128.f) - m * m;
        float rs = rsqrtf(var + 1e-3f);
        if (t < 128) {
            float v = (h1raw[t] - m) * rs * g1[t] + be1[t];
            h1n[t] = v; h1nh[t] = (_Float16)v;
        }
    }
    __syncthreads();
    {   // phase B: msh[f] = relu(h1nh . W1[:,f] + b1), one output per thread
        const __half* wp = W1p + t * 8;
        const v2h* hk = (const v2h*)h1nh;
        float acc = 0.f;
        #pragma unroll 8
        for (int kg = 0; kg < 16; ++kg) {
            float4 raw = *(const float4*)(wp + (size_t)kg * 4096);
            const v2h* hp = (const v2h*)&raw;
            acc = fdot2f(hp[0], hk[kg * 4 + 0], acc);
            acc = fdot2f(hp[1], hk[kg * 4 + 1], acc);
            acc = fdot2f(hp[2], hk[kg * 4 + 2], acc);
            acc = fdot2f(hp[3], hk[kg * 4 + 3], acc);
        }
        msh[t] = (_Float16)fmaxf(acc + b1[t], 0.f);
    }
    __syncthreads();
    {   // phase C: out[c] = msh . W2[:,c] + b2 + h1n, K=512 in 4 wave-chunks
        const __half* wp = W2p + ((size_t)(kq * 16) * 128 + c) * 8;
        const v2h* mk = (const v2h*)msh + kq * 64;
        float acc = 0.f;
        #pragma unroll 8
        for (int g = 0; g < 16; ++g) {
            float4 raw = *(const float4*)(wp + (size_t)g * 1024);
            const v2h* hp = (const v2h*)&raw;
            acc = fdot2f(hp[0], mk[g * 4 + 0], acc);
            acc = fdot2f(hp[1], mk[g * 4 + 1], acc);
            acc = fdot2f(hp[2], mk[g * 4 + 2], acc);
            acc = fdot2f(hp[3], mk[g * 4 + 3], acc);
        }
        part[kq][c] = acc;
    }
    __syncthreads();
    if (t < 128) {
        float acc = part[0][t] + part[1][t] + part[2][t] + part[3][t];
        h1raw[t] = acc + b2[t] + h1n[t];
    }
    __syncthreads();
    {   // LN2 (redundant per wave) -> global out
        int l = t & 63;
        float a = h1raw[l], bb = h1raw[l + 64];
        float sm = a + bb, sq = a * a + bb * bb;
        #pragma unroll
        for (int off = 32; off; off >>= 1) { sm += __shfl_xor(sm, off); sq += __shfl_xor(sq, off); }
        float m = sm * (1.f / 128.f), var = sq * (1.f / 128.f) - m * m;
        float rs = rsqrtf(var + 1e-3f);
        if (t < 128) out[(size_t)b * 128 + t] = (h1raw[t] - m) * rs * g2[t] + be2[t];
    }
}

extern "C" void kernel_launch(void* const* d_in, const int* in_sizes, int n_in,
                              void* d_out, int out_size, void* d_ws, size_t ws_size,
                              hipStream_t stream) {
    const float* AF  = (const float*)d_in[0];
    const float* Wq  = (const float*)d_in[1];
    const float* bq  = (const float*)d_in[2];
    const float* Wk  = (const float*)d_in[3];
    const float* Wv  = (const float*)d_in[5];
    const float* bv  = (const float*)d_in[6];
    const float* Wo  = (const float*)d_in[7];
    const float* bo  = (const float*)d_in[8];
    const float* W1  = (const float*)d_in[9];
    const float* b1  = (const float*)d_in[10];
    const float* W2  = (const float*)d_in[11];
    const float* b2  = (const float*)d_in[12];
    const float* g1  = (const float*)d_in[13];
    const float* be1 = (const float*)d_in[14];
    const float* g2  = (const float*)d_in[15];
    const float* be2 = (const float*)d_in[16];
    const int* mol    = (const int*)d_in[17];
    const int* picked = (const int*)d_in[18];
    int N = in_sizes[0] / 128;
    int noff = (N + 255) / 256;

    char* ws = (char*)d_ws;
    int*    offs = (int*)ws;                      // 513 ints (4KB slot)
    __half* WVOp = (__half*)(ws + 4096);          // packed [128][128][8] 256KB
    __half* WQKp = (__half*)(ws + 266240);        // packed [128][128][8] 256KB
    float*  bqk  = (float*)(ws + 528384);         // [8][128] 4KB
    float*  bvoP = (float*)(ws + 532480);         // [8][128] 4KB
    __half* W1p  = (__half*)(ws + 536576);        // packed [16][512][8] 128KB
    __half* W2p  = (__half*)(ws + 667648);        // packed [64][128][8] 128KB

    k_front<<<336 + noff, 256, 0, stream>>>(Wq, bq, Wk, Wv, Wo, bv, W1, W2,
                                            mol, N, noff,
                                            offs, WVOp, WQKp, bqk, bvoP, W1p, W2p);
    k_attn_tail<<<BMOL, 512, 0, stream>>>(AF, offs, picked, WQKp, bqk,
                                          WVOp, bvoP, bo, g1, be1, W1p, b1,
                                          W2p, b2, g2, be2, (float*)d_out);
}